// Round 4
// baseline (119.129 us; speedup 1.0000x reference)
//
#include <hip/hip_runtime.h>
#include <math.h>

#define BPB 128   // blocks per batch per pass
#define NACC 17   // |w|, w, wX(3) | wY(3), wY_i X_j(9)

typedef float  floatx4 __attribute__((ext_vector_type(4)));
typedef int    intx4   __attribute__((ext_vector_type(4)));
typedef unsigned long long ullx2 __attribute__((ext_vector_type(2)));

// 16-byte point load with only 4-byte alignment guarantee (addr = base + 12*idx).
struct __attribute__((packed, aligned(4))) f4 { float x, y, z, w; };

__device__ __forceinline__ void gather_pt(const float* __restrict__ base, int idx,
                                          bool guard, int M1,
                                          float& p0, float& p1, float& p2)
{
    const size_t o = 3 * (size_t)idx;
    if (guard && __builtin_expect(idx == M1, 0)) {
        p0 = base[o]; p1 = base[o + 1]; p2 = base[o + 2];
    } else {
        const f4 v = *(const f4*)(base + o);   // one dwordx4 gather
        p0 = v.x; p1 = v.y; p2 = v.z;
    }
}

__device__ __forceinline__ void xcd_map(int B, int& b, int& ib)
{
    // batch b's blocks all hit XCD b%8 (round-robin dispatch) -> per-XCD L2
    // holds ONE batch's single-cloud working set (2.4 MB < 4 MB L2).
    if ((B & 7) == 0) {
        const int grp = blockIdx.x / (8 * BPB);
        const int r   = blockIdx.x % (8 * BPB);
        b  = grp * 8 + (r & 7);
        ib = r >> 3;
    } else {
        b  = blockIdx.x % B;
        ib = blockIdx.x / B;
    }
}

// ---------------- PASS 1: gather X, emit (wX, w) records + j ----------------
template <bool GUARD>
__device__ __forceinline__ void p1_loop(
    const float* __restrict__ x1b,
    const ullx2* __restrict__ pv, const floatx4* __restrict__ wv,
    floatx4* __restrict__ recb, intx4* __restrict__ jvb,
    int c0, int stride, int nChunks, int M1, float acc[5])
{
    for (int c = c0; c < nChunks; c += stride) {
        const ullx2  pA = __builtin_nontemporal_load(&pv[2 * c]);
        const ullx2  pB = __builtin_nontemporal_load(&pv[2 * c + 1]);
        const floatx4 w4 = __builtin_nontemporal_load(&wv[c]);

        int ix[4];
        intx4 j4;
        ix[0] = (int)(unsigned)(pA.x & 0xffffffffu); j4.x = (int)(unsigned)(pA.x >> 32);
        ix[1] = (int)(unsigned)(pA.y & 0xffffffffu); j4.y = (int)(unsigned)(pA.y >> 32);
        ix[2] = (int)(unsigned)(pB.x & 0xffffffffu); j4.z = (int)(unsigned)(pB.x >> 32);
        ix[3] = (int)(unsigned)(pB.y & 0xffffffffu); j4.w = (int)(unsigned)(pB.y >> 32);

        float X[4][3];
#pragma unroll
        for (int u = 0; u < 4; ++u)
            gather_pt(x1b, ix[u], GUARD, M1, X[u][0], X[u][1], X[u][2]);

#pragma unroll
        for (int u = 0; u < 4; ++u) {
            const float w = w4[u];
            acc[0] += fabsf(w);
            acc[1] += w;
            const float wx0 = w * X[u][0], wx1 = w * X[u][1], wx2 = w * X[u][2];
            acc[2] += wx0; acc[3] += wx1; acc[4] += wx2;
            floatx4 r; r.x = wx0; r.y = wx1; r.z = wx2; r.w = w;
            __builtin_nontemporal_store(r, &recb[4 * c + u]);
        }
        __builtin_nontemporal_store(j4, &jvb[c]);
    }
}

__global__ __launch_bounds__(256) void wp_pass1(
    const float* __restrict__ xyzs1,
    const int*   __restrict__ pairs,
    const float* __restrict__ weights,
    floatx4* __restrict__ recs,
    intx4*   __restrict__ jarr,
    float* __restrict__ partials,
    int B, int M, int N)
{
    int b, ib; xcd_map(B, b, ib);
    const int tid = threadIdx.x;

    const float* __restrict__ x1b = xyzs1 + (size_t)b * M * 3;
    const ullx2* __restrict__ pv  = (const ullx2*)(pairs + (size_t)b * N * 2);
    const floatx4* __restrict__ wv = (const floatx4*)(weights + (size_t)b * N);
    floatx4* __restrict__ recb = recs + (size_t)b * N;
    intx4*   __restrict__ jvb  = jarr + ((size_t)b * N >> 2);

    const bool lastBatch = (b == B - 1);
    const int  M1 = M - 1;
    const int  nChunks = N >> 2;

    float acc[5];
#pragma unroll
    for (int k = 0; k < 5; ++k) acc[k] = 0.f;

    const int c0 = ib * 256 + tid;
    if (lastBatch) p1_loop<true >(x1b, pv, wv, recb, jvb, c0, BPB * 256, nChunks, M1, acc);
    else           p1_loop<false>(x1b, pv, wv, recb, jvb, c0, BPB * 256, nChunks, M1, acc);

    // scalar tail (N % 4)
    const int* pb = (const int*)pv;
    const float* wb = (const float*)wv;
    float* recf = (float*)recb;
    int*   jf   = (int*)jvb;
    for (int n = (nChunks << 2) + ib * 256 + tid; n < N; n += BPB * 256) {
        const int ixt = pb[2 * n], iyt = pb[2 * n + 1];
        const float w = wb[n];
        float X0, X1, X2;
        gather_pt(x1b, ixt, true, M1, X0, X1, X2);
        acc[0] += fabsf(w); acc[1] += w;
        const float wx0 = w * X0, wx1 = w * X1, wx2 = w * X2;
        acc[2] += wx0; acc[3] += wx1; acc[4] += wx2;
        recf[4 * n] = wx0; recf[4 * n + 1] = wx1; recf[4 * n + 2] = wx2; recf[4 * n + 3] = w;
        jf[n] = iyt;
    }

#pragma unroll
    for (int k = 0; k < 5; ++k) {
#pragma unroll
        for (int off = 32; off > 0; off >>= 1)
            acc[k] += __shfl_down(acc[k], off);
    }
    __shared__ float red[4][5];
    const int wave = tid >> 6, lane = tid & 63;
    if (lane == 0) {
#pragma unroll
        for (int k = 0; k < 5; ++k) red[wave][k] = acc[k];
    }
    __syncthreads();
    if (tid < 5) {
        const float s = red[0][tid] + red[1][tid] + red[2][tid] + red[3][tid];
        partials[((size_t)b * BPB + ib) * NACC + tid] = s;
    }
}

// ---------------- PASS 2: stream records, gather Y ----------------
template <bool GUARD>
__device__ __forceinline__ void p2_loop(
    const float* __restrict__ x2b,
    const floatx4* __restrict__ recb, const intx4* __restrict__ jvb,
    int c0, int stride, int nChunks, int M1, float acc[12])
{
    for (int c = c0; c < nChunks; c += stride) {
        const intx4 j4 = __builtin_nontemporal_load(&jvb[c]);
        floatx4 r[4];
#pragma unroll
        for (int u = 0; u < 4; ++u)
            r[u] = __builtin_nontemporal_load(&recb[4 * c + u]);

        int jy[4] = {j4.x, j4.y, j4.z, j4.w};
        float Y[4][3];
#pragma unroll
        for (int u = 0; u < 4; ++u)
            gather_pt(x2b, jy[u], GUARD, M1, Y[u][0], Y[u][1], Y[u][2]);

#pragma unroll
        for (int u = 0; u < 4; ++u) {
            const float w = r[u].w;
            acc[0] += w * Y[u][0];
            acc[1] += w * Y[u][1];
            acc[2] += w * Y[u][2];
#pragma unroll
            for (int i = 0; i < 3; ++i) {
                acc[3 + 3 * i]     += Y[u][i] * r[u].x;
                acc[3 + 3 * i + 1] += Y[u][i] * r[u].y;
                acc[3 + 3 * i + 2] += Y[u][i] * r[u].z;
            }
        }
    }
}

__global__ __launch_bounds__(256) void wp_pass2(
    const float* __restrict__ xyzs2,
    const floatx4* __restrict__ recs,
    const intx4*   __restrict__ jarr,
    float* __restrict__ partials,
    int B, int M, int N)
{
    int b, ib; xcd_map(B, b, ib);
    const int tid = threadIdx.x;

    const float* __restrict__ x2b = xyzs2 + (size_t)b * M * 3;
    const floatx4* __restrict__ recb = recs + (size_t)b * N;
    const intx4*   __restrict__ jvb  = jarr + ((size_t)b * N >> 2);

    const bool lastBatch = (b == B - 1);
    const int  M1 = M - 1;
    const int  nChunks = N >> 2;

    float acc[12];
#pragma unroll
    for (int k = 0; k < 12; ++k) acc[k] = 0.f;

    const int c0 = ib * 256 + tid;
    if (lastBatch) p2_loop<true >(x2b, recb, jvb, c0, BPB * 256, nChunks, M1, acc);
    else           p2_loop<false>(x2b, recb, jvb, c0, BPB * 256, nChunks, M1, acc);

    // scalar tail
    const float* recf = (const float*)recb;
    const int*   jf   = (const int*)jvb;
    for (int n = (nChunks << 2) + ib * 256 + tid; n < N; n += BPB * 256) {
        const int jyt = jf[n];
        const float wx0 = recf[4 * n], wx1 = recf[4 * n + 1], wx2 = recf[4 * n + 2], w = recf[4 * n + 3];
        float Y0, Y1, Y2;
        gather_pt(x2b, jyt, true, M1, Y0, Y1, Y2);
        acc[0] += w * Y0; acc[1] += w * Y1; acc[2] += w * Y2;
        acc[3] += Y0 * wx0; acc[4]  += Y0 * wx1; acc[5]  += Y0 * wx2;
        acc[6] += Y1 * wx0; acc[7]  += Y1 * wx1; acc[8]  += Y1 * wx2;
        acc[9] += Y2 * wx0; acc[10] += Y2 * wx1; acc[11] += Y2 * wx2;
    }

#pragma unroll
    for (int k = 0; k < 12; ++k) {
#pragma unroll
        for (int off = 32; off > 0; off >>= 1)
            acc[k] += __shfl_down(acc[k], off);
    }
    __shared__ float red[4][12];
    const int wave = tid >> 6, lane = tid & 63;
    if (lane == 0) {
#pragma unroll
        for (int k = 0; k < 12; ++k) red[wave][k] = acc[k];
    }
    __syncthreads();
    if (tid < 12) {
        const float s = red[0][tid] + red[1][tid] + red[2][tid] + red[3][tid];
        partials[((size_t)b * BPB + ib) * NACC + 5 + tid] = s;
    }
}

// ---------------- fallback single-pass (if workspace too small) ----------------
template <bool GUARD>
__device__ __forceinline__ void wp_loop1(
    const float* __restrict__ x1b, const float* __restrict__ x2b,
    const ullx2* __restrict__ pv, const floatx4* __restrict__ wv,
    int c0, int stride, int nChunks, int M1, float acc[NACC])
{
    for (int c = c0; c < nChunks; c += stride) {
        const ullx2  pA = __builtin_nontemporal_load(&pv[2 * c]);
        const ullx2  pB = __builtin_nontemporal_load(&pv[2 * c + 1]);
        const floatx4 w4 = __builtin_nontemporal_load(&wv[c]);
        int ix[4], iy[4];
        ix[0] = (int)(unsigned)(pA.x & 0xffffffffu); iy[0] = (int)(unsigned)(pA.x >> 32);
        ix[1] = (int)(unsigned)(pA.y & 0xffffffffu); iy[1] = (int)(unsigned)(pA.y >> 32);
        ix[2] = (int)(unsigned)(pB.x & 0xffffffffu); iy[2] = (int)(unsigned)(pB.x >> 32);
        ix[3] = (int)(unsigned)(pB.y & 0xffffffffu); iy[3] = (int)(unsigned)(pB.y >> 32);
        float X[4][3], Y[4][3];
#pragma unroll
        for (int u = 0; u < 4; ++u) gather_pt(x1b, ix[u], GUARD, M1, X[u][0], X[u][1], X[u][2]);
#pragma unroll
        for (int u = 0; u < 4; ++u) gather_pt(x2b, iy[u], GUARD, M1, Y[u][0], Y[u][1], Y[u][2]);
#pragma unroll
        for (int u = 0; u < 4; ++u) {
            const float w = w4[u];
            acc[0] += fabsf(w); acc[1] += w;
            acc[2] += w * X[u][0]; acc[3] += w * X[u][1]; acc[4] += w * X[u][2];
            const float wy0 = w * Y[u][0], wy1 = w * Y[u][1], wy2 = w * Y[u][2];
            acc[5] += wy0; acc[6] += wy1; acc[7] += wy2;
            acc[8]  += wy0 * X[u][0]; acc[9]  += wy0 * X[u][1]; acc[10] += wy0 * X[u][2];
            acc[11] += wy1 * X[u][0]; acc[12] += wy1 * X[u][1]; acc[13] += wy1 * X[u][2];
            acc[14] += wy2 * X[u][0]; acc[15] += wy2 * X[u][1]; acc[16] += wy2 * X[u][2];
        }
    }
}

__global__ __launch_bounds__(256) void wp_partials(
    const float* __restrict__ xyzs1,
    const float* __restrict__ xyzs2,
    const int*   __restrict__ pairs,
    const float* __restrict__ weights,
    float* __restrict__ partials,
    int B, int M, int N)
{
    int b, ib; xcd_map(B, b, ib);
    const int tid = threadIdx.x;
    const float* __restrict__ x1b = xyzs1 + (size_t)b * M * 3;
    const float* __restrict__ x2b = xyzs2 + (size_t)b * M * 3;
    const ullx2* __restrict__ pv  = (const ullx2*)(pairs + (size_t)b * N * 2);
    const floatx4* __restrict__ wv = (const floatx4*)(weights + (size_t)b * N);
    const bool lastBatch = (b == B - 1);
    const int  M1 = M - 1;
    const int  nChunks = N >> 2;
    float acc[NACC];
#pragma unroll
    for (int k = 0; k < NACC; ++k) acc[k] = 0.f;
    const int c0 = ib * 256 + tid;
    if (lastBatch) wp_loop1<true >(x1b, x2b, pv, wv, c0, BPB * 256, nChunks, M1, acc);
    else           wp_loop1<false>(x1b, x2b, pv, wv, c0, BPB * 256, nChunks, M1, acc);
    const int* pb = (const int*)pv;
    const float* wb = (const float*)wv;
    for (int n = (nChunks << 2) + ib * 256 + tid; n < N; n += BPB * 256) {
        const int ixt = pb[2 * n], iyt = pb[2 * n + 1];
        const float w = wb[n];
        float X0, X1, X2, Y0, Y1, Y2;
        gather_pt(x1b, ixt, true, M1, X0, X1, X2);
        gather_pt(x2b, iyt, true, M1, Y0, Y1, Y2);
        acc[0] += fabsf(w); acc[1] += w;
        acc[2] += w * X0; acc[3] += w * X1; acc[4] += w * X2;
        const float wy0 = w * Y0, wy1 = w * Y1, wy2 = w * Y2;
        acc[5] += wy0; acc[6] += wy1; acc[7] += wy2;
        acc[8]  += wy0 * X0; acc[9]  += wy0 * X1; acc[10] += wy0 * X2;
        acc[11] += wy1 * X0; acc[12] += wy1 * X1; acc[13] += wy1 * X2;
        acc[14] += wy2 * X0; acc[15] += wy2 * X1; acc[16] += wy2 * X2;
    }
#pragma unroll
    for (int k = 0; k < NACC; ++k) {
#pragma unroll
        for (int off = 32; off > 0; off >>= 1)
            acc[k] += __shfl_down(acc[k], off);
    }
    __shared__ float red[4][NACC];
    const int wave = tid >> 6, lane = tid & 63;
    if (lane == 0) {
#pragma unroll
        for (int k = 0; k < NACC; ++k) red[wave][k] = acc[k];
    }
    __syncthreads();
    if (tid < NACC) {
        const float s = red[0][tid] + red[1][tid] + red[2][tid] + red[3][tid];
        partials[((size_t)b * BPB + ib) * NACC + tid] = s;
    }
}

// ---------------- finalize (3x3 SVD etc., unchanged) ----------------
__global__ __launch_bounds__(64) void wp_finalize(
    const float* __restrict__ partials,
    float* __restrict__ out,
    int B)
{
    const int b = blockIdx.x;
    const int t = threadIdx.x;

    double acc[NACC];
#pragma unroll
    for (int k = 0; k < NACC; ++k) acc[k] = 0.0;

    const float* __restrict__ p = partials + (size_t)b * BPB * NACC;
    for (int i = t; i < BPB; i += 64) {
#pragma unroll
        for (int k = 0; k < NACC; ++k) acc[k] += (double)p[i * NACC + k];
    }
#pragma unroll
    for (int k = 0; k < NACC; ++k) {
#pragma unroll
        for (int off = 32; off > 0; off >>= 1)
            acc[k] += __shfl_down(acc[k], off);
    }

    if (t != 0) return;

    const double EPS = 1.1920928955078125e-07;  // np.float32 eps
    const double W1 = acc[0];
    const double Sw = acc[1];
    const double inv = 1.0 / (W1 + EPS);
    const double mux[3] = {acc[2] * inv, acc[3] * inv, acc[4] * inv};
    const double muy[3] = {acc[5] * inv, acc[6] * inv, acc[7] * inv};
    const double S0 = Sw * inv;
    const double c2 = 2.0 - S0;

    double S[3][3];
#pragma unroll
    for (int i = 0; i < 3; ++i)
#pragma unroll
        for (int j = 0; j < 3; ++j)
            S[i][j] = acc[8 + i * 3 + j] * inv - muy[i] * mux[j] * c2;

    double A[3][3];
#pragma unroll
    for (int i = 0; i < 3; ++i)
#pragma unroll
        for (int j = 0; j < 3; ++j)
            A[i][j] = S[0][i] * S[0][j] + S[1][i] * S[1][j] + S[2][i] * S[2][j];

    double V[3][3] = {{1, 0, 0}, {0, 1, 0}, {0, 0, 1}};
    for (int sweep = 0; sweep < 30; ++sweep) {
        const double offd = fabs(A[0][1]) + fabs(A[0][2]) + fabs(A[1][2]);
        if (offd == 0.0) break;
        for (int pq = 0; pq < 3; ++pq) {
            const int pi = (pq == 2) ? 1 : 0;
            const int qi = (pq == 0) ? 1 : 2;
            const double apq = A[pi][qi];
            if (fabs(apq) < 1e-300) continue;
            const double theta = (A[qi][qi] - A[pi][pi]) / (2.0 * apq);
            const double tt = copysign(1.0, theta) / (fabs(theta) + sqrt(theta * theta + 1.0));
            const double c = 1.0 / sqrt(tt * tt + 1.0);
            const double s = tt * c;
            const int r = 3 - pi - qi;
            A[pi][pi] -= tt * apq;
            A[qi][qi] += tt * apq;
            A[pi][qi] = A[qi][pi] = 0.0;
            const double arp = A[r][pi], arq = A[r][qi];
            A[r][pi] = A[pi][r] = c * arp - s * arq;
            A[r][qi] = A[qi][r] = s * arp + c * arq;
#pragma unroll
            for (int k = 0; k < 3; ++k) {
                const double vkp = V[k][pi], vkq = V[k][qi];
                V[k][pi] = c * vkp - s * vkq;
                V[k][qi] = s * vkp + c * vkq;
            }
        }
    }

    double lam[3] = {A[0][0], A[1][1], A[2][2]};
    int idx[3] = {0, 1, 2};
    if (lam[idx[0]] < lam[idx[1]]) { int q = idx[0]; idx[0] = idx[1]; idx[1] = q; }
    if (lam[idx[0]] < lam[idx[2]]) { int q = idx[0]; idx[0] = idx[2]; idx[2] = q; }
    if (lam[idx[1]] < lam[idx[2]]) { int q = idx[1]; idx[1] = idx[2]; idx[2] = q; }

    const double v0[3] = {V[0][idx[0]], V[1][idx[0]], V[2][idx[0]]};
    const double v1[3] = {V[0][idx[1]], V[1][idx[1]], V[2][idx[1]]};

    double u0[3], u1[3];
#pragma unroll
    for (int i = 0; i < 3; ++i) u0[i] = S[i][0] * v0[0] + S[i][1] * v0[1] + S[i][2] * v0[2];
    {
        const double n2 = u0[0] * u0[0] + u0[1] * u0[1] + u0[2] * u0[2];
        const double in0 = 1.0 / sqrt(fmax(n2, 1e-300));
        u0[0] *= in0; u0[1] *= in0; u0[2] *= in0;
    }
#pragma unroll
    for (int i = 0; i < 3; ++i) u1[i] = S[i][0] * v1[0] + S[i][1] * v1[1] + S[i][2] * v1[2];
    {
        const double d01 = u1[0] * u0[0] + u1[1] * u0[1] + u1[2] * u0[2];
        u1[0] -= d01 * u0[0]; u1[1] -= d01 * u0[1]; u1[2] -= d01 * u0[2];
        const double n2 = u1[0] * u1[0] + u1[1] * u1[1] + u1[2] * u1[2];
        const double in1 = 1.0 / sqrt(fmax(n2, 1e-300));
        u1[0] *= in1; u1[1] *= in1; u1[2] *= in1;
    }
    const double u2[3] = {u0[1] * u1[2] - u0[2] * u1[1],
                          u0[2] * u1[0] - u0[0] * u1[2],
                          u0[0] * u1[1] - u0[1] * u1[0]};
    const double v2[3] = {v0[1] * v1[2] - v0[2] * v1[1],
                          v0[2] * v1[0] - v0[0] * v1[2],
                          v0[0] * v1[1] - v0[1] * v1[0]};

    double R[3][3];
#pragma unroll
    for (int i = 0; i < 3; ++i)
#pragma unroll
        for (int j = 0; j < 3; ++j)
            R[i][j] = u0[i] * v0[j] + u1[i] * v1[j] + u2[i] * v2[j];

    double tv[3];
#pragma unroll
    for (int i = 0; i < 3; ++i)
        tv[i] = muy[i] - (R[i][0] * mux[0] + R[i][1] * mux[1] + R[i][2] * mux[2]);

    float* __restrict__ Rout = out + (size_t)b * 9;
#pragma unroll
    for (int i = 0; i < 3; ++i)
#pragma unroll
        for (int j = 0; j < 3; ++j)
            Rout[i * 3 + j] = (float)R[i][j];
    float* __restrict__ tout = out + (size_t)B * 9 + (size_t)b * 3;
#pragma unroll
    for (int i = 0; i < 3; ++i) tout[i] = (float)tv[i];
    out[(size_t)B * 12 + b] = (float)Sw;
}

extern "C" void kernel_launch(void* const* d_in, const int* in_sizes, int n_in,
                              void* d_out, int out_size, void* d_ws, size_t ws_size,
                              hipStream_t stream) {
    const float* xyzs1   = (const float*)d_in[0];
    const float* xyzs2   = (const float*)d_in[1];
    const int*   pairs   = (const int*)d_in[2];
    const float* weights = (const float*)d_in[3];
    float* out = (float*)d_out;

    const int B = out_size / 13;           // 9 + 3 + 1 floats per batch
    const int M = in_sizes[0] / (3 * B);
    const int N = in_sizes[3] / B;

    const size_t recBytes  = (size_t)B * N * 16;   // float4 (wX, w) per pair
    const size_t jBytes    = (size_t)B * N * 4;    // j per pair
    const size_t partBytes = (size_t)B * BPB * NACC * 4;

    if (ws_size >= recBytes + jBytes + partBytes) {
        floatx4* recs = (floatx4*)d_ws;
        intx4*   jarr = (intx4*)((char*)d_ws + recBytes);
        float* partials = (float*)((char*)d_ws + recBytes + jBytes);
        hipLaunchKernelGGL(wp_pass1, dim3(B * BPB), dim3(256), 0, stream,
                           xyzs1, pairs, weights, recs, jarr, partials, B, M, N);
        hipLaunchKernelGGL(wp_pass2, dim3(B * BPB), dim3(256), 0, stream,
                           xyzs2, recs, jarr, partials, B, M, N);
        hipLaunchKernelGGL(wp_finalize, dim3(B), dim3(64), 0, stream,
                           partials, out, B);
    } else {
        float* partials = (float*)d_ws;    // B * BPB * NACC floats
        hipLaunchKernelGGL(wp_partials, dim3(B * BPB), dim3(256), 0, stream,
                           xyzs1, xyzs2, pairs, weights, partials, B, M, N);
        hipLaunchKernelGGL(wp_finalize, dim3(B), dim3(64), 0, stream,
                           partials, out, B);
    }
}

// Round 5
// 72.425 us; speedup vs baseline: 1.6449x; 1.6449x over previous
//
#include <hip/hip_runtime.h>
#include <math.h>

#define BPB 128   // blocks per batch (stage-1)
#define NACC 17   // accumulators: |w|, w, wX(3), wY(3), wY_i X_j (9)

typedef float  floatx4 __attribute__((ext_vector_type(4)));
typedef unsigned long long ullx2 __attribute__((ext_vector_type(2)));

// 16-byte point load with only 4-byte alignment guarantee (addr = base + 12*idx).
struct __attribute__((packed, aligned(4))) f4 { float x, y, z, w; };

__device__ __forceinline__ void gather_pt(const float* __restrict__ base, int idx,
                                          bool guard, int M1,
                                          float& p0, float& p1, float& p2)
{
    const size_t o = 3 * (size_t)idx;
    if (guard && __builtin_expect(idx == M1, 0)) {
        p0 = base[o]; p1 = base[o + 1]; p2 = base[o + 2];
    } else {
        const f4 v = *(const f4*)(base + o);   // one dwordx4 gather
        p0 = v.x; p1 = v.y; p2 = v.z;
    }
}

template <bool GUARD>
__device__ __forceinline__ void wp_loop(
    const float* __restrict__ x1b, const float* __restrict__ x2b,
    const ullx2* __restrict__ pv, const floatx4* __restrict__ wv,
    int c0, int stride, int nChunks, int M1, float acc[NACC])
{
    for (int c = c0; c < nChunks; c += stride) {
        // streamed once: nontemporal keeps pair/weight lines from polluting caches
        const ullx2  pA = __builtin_nontemporal_load(&pv[2 * c]);
        const ullx2  pB = __builtin_nontemporal_load(&pv[2 * c + 1]);
        const floatx4 w4 = __builtin_nontemporal_load(&wv[c]);

        int ix[4], iy[4];
        ix[0] = (int)(unsigned)(pA.x & 0xffffffffu); iy[0] = (int)(unsigned)(pA.x >> 32);
        ix[1] = (int)(unsigned)(pA.y & 0xffffffffu); iy[1] = (int)(unsigned)(pA.y >> 32);
        ix[2] = (int)(unsigned)(pB.x & 0xffffffffu); iy[2] = (int)(unsigned)(pB.x >> 32);
        ix[3] = (int)(unsigned)(pB.y & 0xffffffffu); iy[3] = (int)(unsigned)(pB.y >> 32);

        float X[4][3], Y[4][3];
#pragma unroll
        for (int u = 0; u < 4; ++u)
            gather_pt(x1b, ix[u], GUARD, M1, X[u][0], X[u][1], X[u][2]);
#pragma unroll
        for (int u = 0; u < 4; ++u)
            gather_pt(x2b, iy[u], GUARD, M1, Y[u][0], Y[u][1], Y[u][2]);

#pragma unroll
        for (int u = 0; u < 4; ++u) {
            const float w = w4[u];
            acc[0] += fabsf(w);
            acc[1] += w;
            acc[2] += w * X[u][0];
            acc[3] += w * X[u][1];
            acc[4] += w * X[u][2];
            const float wy0 = w * Y[u][0], wy1 = w * Y[u][1], wy2 = w * Y[u][2];
            acc[5] += wy0; acc[6] += wy1; acc[7] += wy2;
            acc[8]  += wy0 * X[u][0]; acc[9]  += wy0 * X[u][1]; acc[10] += wy0 * X[u][2];
            acc[11] += wy1 * X[u][0]; acc[12] += wy1 * X[u][1]; acc[13] += wy1 * X[u][2];
            acc[14] += wy2 * X[u][0]; acc[15] += wy2 * X[u][1]; acc[16] += wy2 * X[u][2];
        }
    }
}

// One launch handles nb batches starting at b0. When nb==8, batch b0+k's
// blocks all have blockIdx%8==k -> one batch per XCD; per-XCD gather working
// set = X+Y of ONE batch (4.8 MB ~ L2). Sequential launches keep the other
// batch group off-chip until this one finishes (temporal partitioning).
__global__ __launch_bounds__(256) void wp_partials(
    const float* __restrict__ xyzs1,
    const float* __restrict__ xyzs2,
    const int*   __restrict__ pairs,
    const float* __restrict__ weights,
    float* __restrict__ partials,
    int B, int M, int N, int b0, int nb)
{
    int b, ib;
    if (nb == 8) {
        b  = b0 + (blockIdx.x & 7);
        ib = blockIdx.x >> 3;
    } else {
        b  = b0 + (int)(blockIdx.x % nb);
        ib = blockIdx.x / nb;
    }
    const int tid = threadIdx.x;

    const float* __restrict__ x1b = xyzs1 + (size_t)b * M * 3;
    const float* __restrict__ x2b = xyzs2 + (size_t)b * M * 3;
    const ullx2* __restrict__ pv  = (const ullx2*)(pairs + (size_t)b * N * 2);
    const floatx4* __restrict__ wv = (const floatx4*)(weights + (size_t)b * N);

    const bool lastBatch = (b == B - 1);   // global OOB guard only for very last point
    const int  M1 = M - 1;
    const int  nChunks = N >> 2;

    float acc[NACC];
#pragma unroll
    for (int k = 0; k < NACC; ++k) acc[k] = 0.f;

    const int c0 = ib * 256 + tid;
    if (lastBatch)
        wp_loop<true >(x1b, x2b, pv, wv, c0, BPB * 256, nChunks, M1, acc);
    else
        wp_loop<false>(x1b, x2b, pv, wv, c0, BPB * 256, nChunks, M1, acc);

    // tail (N % 4 != 0), scalar + always guarded (rare)
    const int* pb = (const int*)pv;
    const float* wb = (const float*)wv;
    for (int n = (nChunks << 2) + ib * 256 + tid; n < N; n += BPB * 256) {
        const int ixt = pb[2 * n], iyt = pb[2 * n + 1];
        const float w = wb[n];
        float X0, X1, X2, Y0, Y1, Y2;
        gather_pt(x1b, ixt, true, M1, X0, X1, X2);
        gather_pt(x2b, iyt, true, M1, Y0, Y1, Y2);
        acc[0] += fabsf(w); acc[1] += w;
        acc[2] += w * X0; acc[3] += w * X1; acc[4] += w * X2;
        const float wy0 = w * Y0, wy1 = w * Y1, wy2 = w * Y2;
        acc[5] += wy0; acc[6] += wy1; acc[7] += wy2;
        acc[8]  += wy0 * X0; acc[9]  += wy0 * X1; acc[10] += wy0 * X2;
        acc[11] += wy1 * X0; acc[12] += wy1 * X1; acc[13] += wy1 * X2;
        acc[14] += wy2 * X0; acc[15] += wy2 * X1; acc[16] += wy2 * X2;
    }

    // wave (64-lane) tree reduction
#pragma unroll
    for (int k = 0; k < NACC; ++k) {
#pragma unroll
        for (int off = 32; off > 0; off >>= 1)
            acc[k] += __shfl_down(acc[k], off);
    }

    __shared__ float red[4][NACC];
    const int wave = tid >> 6, lane = tid & 63;
    if (lane == 0) {
#pragma unroll
        for (int k = 0; k < NACC; ++k) red[wave][k] = acc[k];
    }
    __syncthreads();
    if (tid < NACC) {
        const float s = red[0][tid] + red[1][tid] + red[2][tid] + red[3][tid];
        partials[((size_t)b * BPB + ib) * NACC + tid] = s;
    }
}

__global__ __launch_bounds__(64) void wp_finalize(
    const float* __restrict__ partials,
    float* __restrict__ out,
    int B)
{
    const int b = blockIdx.x;
    const int t = threadIdx.x;

    double acc[NACC];
#pragma unroll
    for (int k = 0; k < NACC; ++k) acc[k] = 0.0;

    const float* __restrict__ p = partials + (size_t)b * BPB * NACC;
    for (int i = t; i < BPB; i += 64) {
#pragma unroll
        for (int k = 0; k < NACC; ++k) acc[k] += (double)p[i * NACC + k];
    }
#pragma unroll
    for (int k = 0; k < NACC; ++k) {
#pragma unroll
        for (int off = 32; off > 0; off >>= 1)
            acc[k] += __shfl_down(acc[k], off);
    }

    if (t != 0) return;

    const double EPS = 1.1920928955078125e-07;  // np.float32 eps
    const double W1 = acc[0];
    const double Sw = acc[1];
    const double inv = 1.0 / (W1 + EPS);
    const double mux[3] = {acc[2] * inv, acc[3] * inv, acc[4] * inv};
    const double muy[3] = {acc[5] * inv, acc[6] * inv, acc[7] * inv};
    const double S0 = Sw * inv;
    const double c2 = 2.0 - S0;

    double S[3][3];
#pragma unroll
    for (int i = 0; i < 3; ++i)
#pragma unroll
        for (int j = 0; j < 3; ++j)
            S[i][j] = acc[8 + i * 3 + j] * inv - muy[i] * mux[j] * c2;

    // A = S^T S (symmetric PSD)
    double A[3][3];
#pragma unroll
    for (int i = 0; i < 3; ++i)
#pragma unroll
        for (int j = 0; j < 3; ++j)
            A[i][j] = S[0][i] * S[0][j] + S[1][i] * S[1][j] + S[2][i] * S[2][j];

    double V[3][3] = {{1, 0, 0}, {0, 1, 0}, {0, 0, 1}};
    for (int sweep = 0; sweep < 30; ++sweep) {
        const double offd = fabs(A[0][1]) + fabs(A[0][2]) + fabs(A[1][2]);
        if (offd == 0.0) break;
        for (int pq = 0; pq < 3; ++pq) {
            const int pi = (pq == 2) ? 1 : 0;
            const int qi = (pq == 0) ? 1 : 2;
            const double apq = A[pi][qi];
            if (fabs(apq) < 1e-300) continue;
            const double theta = (A[qi][qi] - A[pi][pi]) / (2.0 * apq);
            const double tt = copysign(1.0, theta) / (fabs(theta) + sqrt(theta * theta + 1.0));
            const double c = 1.0 / sqrt(tt * tt + 1.0);
            const double s = tt * c;
            const int r = 3 - pi - qi;
            A[pi][pi] -= tt * apq;
            A[qi][qi] += tt * apq;
            A[pi][qi] = A[qi][pi] = 0.0;
            const double arp = A[r][pi], arq = A[r][qi];
            A[r][pi] = A[pi][r] = c * arp - s * arq;
            A[r][qi] = A[qi][r] = s * arp + c * arq;
#pragma unroll
            for (int k = 0; k < 3; ++k) {
                const double vkp = V[k][pi], vkq = V[k][qi];
                V[k][pi] = c * vkp - s * vkq;
                V[k][qi] = s * vkp + c * vkq;
            }
        }
    }

    // sort eigenpairs descending
    double lam[3] = {A[0][0], A[1][1], A[2][2]};
    int idx[3] = {0, 1, 2};
    if (lam[idx[0]] < lam[idx[1]]) { int q = idx[0]; idx[0] = idx[1]; idx[1] = q; }
    if (lam[idx[0]] < lam[idx[2]]) { int q = idx[0]; idx[0] = idx[2]; idx[2] = q; }
    if (lam[idx[1]] < lam[idx[2]]) { int q = idx[1]; idx[1] = idx[2]; idx[2] = q; }

    const double v0[3] = {V[0][idx[0]], V[1][idx[0]], V[2][idx[0]]};
    const double v1[3] = {V[0][idx[1]], V[1][idx[1]], V[2][idx[1]]};

    // u0 = normalize(S v0); u1 = orthonormalize(S v1 against u0)
    double u0[3], u1[3];
#pragma unroll
    for (int i = 0; i < 3; ++i) u0[i] = S[i][0] * v0[0] + S[i][1] * v0[1] + S[i][2] * v0[2];
    {
        const double n2 = u0[0] * u0[0] + u0[1] * u0[1] + u0[2] * u0[2];
        const double in0 = 1.0 / sqrt(fmax(n2, 1e-300));
        u0[0] *= in0; u0[1] *= in0; u0[2] *= in0;
    }
#pragma unroll
    for (int i = 0; i < 3; ++i) u1[i] = S[i][0] * v1[0] + S[i][1] * v1[1] + S[i][2] * v1[2];
    {
        const double d01 = u1[0] * u0[0] + u1[1] * u0[1] + u1[2] * u0[2];
        u1[0] -= d01 * u0[0]; u1[1] -= d01 * u0[1]; u1[2] -= d01 * u0[2];
        const double n2 = u1[0] * u1[0] + u1[1] * u1[1] + u1[2] * u1[2];
        const double in1 = 1.0 / sqrt(fmax(n2, 1e-300));
        u1[0] *= in1; u1[1] *= in1; u1[2] *= in1;
    }
    const double u2[3] = {u0[1] * u1[2] - u0[2] * u1[1],
                          u0[2] * u1[0] - u0[0] * u1[2],
                          u0[0] * u1[1] - u0[1] * u1[0]};
    const double v2[3] = {v0[1] * v1[2] - v0[2] * v1[1],
                          v0[2] * v1[0] - v0[0] * v1[2],
                          v0[0] * v1[1] - v0[1] * v1[0]};

    // R = u0 v0^T + u1 v1^T + (u0 x u1)(v0 x v1)^T  == U diag(1,1,d) V^T
    double R[3][3];
#pragma unroll
    for (int i = 0; i < 3; ++i)
#pragma unroll
        for (int j = 0; j < 3; ++j)
            R[i][j] = u0[i] * v0[j] + u1[i] * v1[j] + u2[i] * v2[j];

    double tv[3];
#pragma unroll
    for (int i = 0; i < 3; ++i)
        tv[i] = muy[i] - (R[i][0] * mux[0] + R[i][1] * mux[1] + R[i][2] * mux[2]);

    float* __restrict__ Rout = out + (size_t)b * 9;
#pragma unroll
    for (int i = 0; i < 3; ++i)
#pragma unroll
        for (int j = 0; j < 3; ++j)
            Rout[i * 3 + j] = (float)R[i][j];
    float* __restrict__ tout = out + (size_t)B * 9 + (size_t)b * 3;
#pragma unroll
    for (int i = 0; i < 3; ++i) tout[i] = (float)tv[i];
    out[(size_t)B * 12 + b] = (float)Sw;
}

extern "C" void kernel_launch(void* const* d_in, const int* in_sizes, int n_in,
                              void* d_out, int out_size, void* d_ws, size_t ws_size,
                              hipStream_t stream) {
    const float* xyzs1   = (const float*)d_in[0];
    const float* xyzs2   = (const float*)d_in[1];
    const int*   pairs   = (const int*)d_in[2];
    const float* weights = (const float*)d_in[3];
    float* out = (float*)d_out;

    const int B = out_size / 13;           // 9 + 3 + 1 floats per batch
    const int M = in_sizes[0] / (3 * B);
    const int N = in_sizes[3] / B;

    float* partials = (float*)d_ws;        // B * BPB * NACC floats

    if ((B & 7) == 0) {
        // temporal partitioning: 8 batches (one per XCD) per launch
        for (int b0 = 0; b0 < B; b0 += 8) {
            hipLaunchKernelGGL(wp_partials, dim3(8 * BPB), dim3(256), 0, stream,
                               xyzs1, xyzs2, pairs, weights, partials, B, M, N, b0, 8);
        }
    } else {
        hipLaunchKernelGGL(wp_partials, dim3(B * BPB), dim3(256), 0, stream,
                           xyzs1, xyzs2, pairs, weights, partials, B, M, N, 0, B);
    }
    hipLaunchKernelGGL(wp_finalize, dim3(B), dim3(64), 0, stream,
                       partials, out, B);
}

// Round 6
// 70.802 us; speedup vs baseline: 1.6826x; 1.0229x over previous
//
#include <hip/hip_runtime.h>
#include <math.h>

#define BPB  64   // blocks per batch; 16*64=1024 blocks; each thread ~3 chunks
#define NACC 17   // |w|, w, wX(3), wY(3), wY_i X_j (9)
#define UNR  3    // chunks per unrolled iteration -> 24 gathers in flight/lane

typedef float  floatx4 __attribute__((ext_vector_type(4)));
typedef unsigned long long ullx2 __attribute__((ext_vector_type(2)));

// 16-byte point load with only 4-byte alignment guarantee (addr = base + 12*idx).
struct __attribute__((packed, aligned(4))) f4 { float x, y, z, w; };

// Branch-free gather: for idx==M1 load one float earlier and use (y,z,w).
// (3*idx-1)*4 stays 4B-aligned and the 16B window stays in-bounds.
__device__ __forceinline__ void acc_pair(float acc[NACC], float w,
                                         float X0, float X1, float X2,
                                         float Y0, float Y1, float Y2)
{
    acc[0] += fabsf(w);
    acc[1] += w;
    acc[2] += w * X0; acc[3] += w * X1; acc[4] += w * X2;
    const float wy0 = w * Y0, wy1 = w * Y1, wy2 = w * Y2;
    acc[5] += wy0; acc[6] += wy1; acc[7] += wy2;
    acc[8]  += wy0 * X0; acc[9]  += wy0 * X1; acc[10] += wy0 * X2;
    acc[11] += wy1 * X0; acc[12] += wy1 * X1; acc[13] += wy1 * X2;
    acc[14] += wy2 * X0; acc[15] += wy2 * X1; acc[16] += wy2 * X2;
}

__global__ __launch_bounds__(256, 2) void wp_partials(
    const float* __restrict__ xyzs1,
    const float* __restrict__ xyzs2,
    const int*   __restrict__ pairs,
    const float* __restrict__ weights,
    float* __restrict__ partials,
    int B, int M, int N)
{
    // XCD batch-affinity mapping (harmless if dispatch isn't round-robin)
    int b, ib;
    if ((B & 7) == 0) {
        const int grp = blockIdx.x / (8 * BPB);
        const int r   = blockIdx.x % (8 * BPB);
        b  = grp * 8 + (r & 7);
        ib = r >> 3;
    } else {
        b  = blockIdx.x % B;
        ib = blockIdx.x / B;
    }
    const int tid = threadIdx.x;

    const float* __restrict__ x1b = xyzs1 + (size_t)b * M * 3;
    const float* __restrict__ x2b = xyzs2 + (size_t)b * M * 3;
    const ullx2* __restrict__ pv  = (const ullx2*)(pairs + (size_t)b * N * 2);
    const floatx4* __restrict__ wv = (const floatx4*)(weights + (size_t)b * N);

    const int M1 = M - 1;
    const int nChunks = N >> 2;
    const int S = BPB * 256;

    float acc[NACC];
#pragma unroll
    for (int k = 0; k < NACC; ++k) acc[k] = 0.f;

    int c = ib * 256 + tid;

    // ---- unrolled main: UNR chunks = 4*UNR pairs = 8*UNR gathers in flight ----
    for (; c + (UNR - 1) * S < nChunks; c += UNR * S) {
        ullx2 pA[UNR], pB[UNR];
        floatx4 w4[UNR];
#pragma unroll
        for (int u = 0; u < UNR; ++u) {
            const int cu = c + u * S;
            pA[u] = __builtin_nontemporal_load(&pv[2 * cu]);
            pB[u] = __builtin_nontemporal_load(&pv[2 * cu + 1]);
            w4[u] = __builtin_nontemporal_load(&wv[cu]);
        }

        int ix[4 * UNR], iy[4 * UNR];
#pragma unroll
        for (int u = 0; u < UNR; ++u) {
            ix[4 * u]     = (int)(unsigned)(pA[u].x & 0xffffffffu);
            iy[4 * u]     = (int)(unsigned)(pA[u].x >> 32);
            ix[4 * u + 1] = (int)(unsigned)(pA[u].y & 0xffffffffu);
            iy[4 * u + 1] = (int)(unsigned)(pA[u].y >> 32);
            ix[4 * u + 2] = (int)(unsigned)(pB[u].x & 0xffffffffu);
            iy[4 * u + 2] = (int)(unsigned)(pB[u].x >> 32);
            ix[4 * u + 3] = (int)(unsigned)(pB[u].y & 0xffffffffu);
            iy[4 * u + 3] = (int)(unsigned)(pB[u].y >> 32);
        }

        // issue ALL gathers before any consumption
        f4 VX[4 * UNR], VY[4 * UNR];
        int lx[4 * UNR], ly[4 * UNR];
#pragma unroll
        for (int k = 0; k < 4 * UNR; ++k) {
            lx[k] = (ix[k] == M1) ? 1 : 0;
            VX[k] = *(const f4*)(x1b + (3 * (size_t)ix[k] - lx[k]));
        }
#pragma unroll
        for (int k = 0; k < 4 * UNR; ++k) {
            ly[k] = (iy[k] == M1) ? 1 : 0;
            VY[k] = *(const f4*)(x2b + (3 * (size_t)iy[k] - ly[k]));
        }

#pragma unroll
        for (int k = 0; k < 4 * UNR; ++k) {
            const float X0 = lx[k] ? VX[k].y : VX[k].x;
            const float X1 = lx[k] ? VX[k].z : VX[k].y;
            const float X2 = lx[k] ? VX[k].w : VX[k].z;
            const float Y0 = ly[k] ? VY[k].y : VY[k].x;
            const float Y1 = ly[k] ? VY[k].z : VY[k].y;
            const float Y2 = ly[k] ? VY[k].w : VY[k].z;
            acc_pair(acc, w4[k >> 2][k & 3], X0, X1, X2, Y0, Y1, Y2);
        }
    }

    // ---- remainder: single-chunk iterations ----
    for (; c < nChunks; c += S) {
        const ullx2 pA = __builtin_nontemporal_load(&pv[2 * c]);
        const ullx2 pB = __builtin_nontemporal_load(&pv[2 * c + 1]);
        const floatx4 w4 = __builtin_nontemporal_load(&wv[c]);
        int ix[4], iy[4];
        ix[0] = (int)(unsigned)(pA.x & 0xffffffffu); iy[0] = (int)(unsigned)(pA.x >> 32);
        ix[1] = (int)(unsigned)(pA.y & 0xffffffffu); iy[1] = (int)(unsigned)(pA.y >> 32);
        ix[2] = (int)(unsigned)(pB.x & 0xffffffffu); iy[2] = (int)(unsigned)(pB.x >> 32);
        ix[3] = (int)(unsigned)(pB.y & 0xffffffffu); iy[3] = (int)(unsigned)(pB.y >> 32);
        f4 VX[4], VY[4];
        int lx[4], ly[4];
#pragma unroll
        for (int k = 0; k < 4; ++k) {
            lx[k] = (ix[k] == M1) ? 1 : 0;
            VX[k] = *(const f4*)(x1b + (3 * (size_t)ix[k] - lx[k]));
        }
#pragma unroll
        for (int k = 0; k < 4; ++k) {
            ly[k] = (iy[k] == M1) ? 1 : 0;
            VY[k] = *(const f4*)(x2b + (3 * (size_t)iy[k] - ly[k]));
        }
#pragma unroll
        for (int k = 0; k < 4; ++k) {
            const float X0 = lx[k] ? VX[k].y : VX[k].x;
            const float X1 = lx[k] ? VX[k].z : VX[k].y;
            const float X2 = lx[k] ? VX[k].w : VX[k].z;
            const float Y0 = ly[k] ? VY[k].y : VY[k].x;
            const float Y1 = ly[k] ? VY[k].z : VY[k].y;
            const float Y2 = ly[k] ? VY[k].w : VY[k].z;
            acc_pair(acc, w4[k], X0, X1, X2, Y0, Y1, Y2);
        }
    }

    // ---- scalar tail (N % 4 != 0) ----
    const int* pb = (const int*)pv;
    const float* wb = (const float*)wv;
    for (int n = (nChunks << 2) + ib * 256 + tid; n < N; n += S) {
        const int i0 = pb[2 * n], j0 = pb[2 * n + 1];
        const float w = wb[n];
        const int li = (i0 == M1) ? 1 : 0, lj = (j0 == M1) ? 1 : 0;
        const f4 vx = *(const f4*)(x1b + (3 * (size_t)i0 - li));
        const f4 vy = *(const f4*)(x2b + (3 * (size_t)j0 - lj));
        acc_pair(acc, w,
                 li ? vx.y : vx.x, li ? vx.z : vx.y, li ? vx.w : vx.z,
                 lj ? vy.y : vy.x, lj ? vy.z : vy.y, lj ? vy.w : vy.z);
    }

    // wave (64-lane) tree reduction
#pragma unroll
    for (int k = 0; k < NACC; ++k) {
#pragma unroll
        for (int off = 32; off > 0; off >>= 1)
            acc[k] += __shfl_down(acc[k], off);
    }

    __shared__ float red[4][NACC];
    const int wave = tid >> 6, lane = tid & 63;
    if (lane == 0) {
#pragma unroll
        for (int k = 0; k < NACC; ++k) red[wave][k] = acc[k];
    }
    __syncthreads();
    if (tid < NACC) {
        const float s = red[0][tid] + red[1][tid] + red[2][tid] + red[3][tid];
        partials[((size_t)b * BPB + ib) * NACC + tid] = s;
    }
}

__global__ __launch_bounds__(64) void wp_finalize(
    const float* __restrict__ partials,
    float* __restrict__ out,
    int B)
{
    const int b = blockIdx.x;
    const int t = threadIdx.x;

    double acc[NACC];
#pragma unroll
    for (int k = 0; k < NACC; ++k) acc[k] = 0.0;

    const float* __restrict__ p = partials + (size_t)b * BPB * NACC;
    for (int i = t; i < BPB; i += 64) {
#pragma unroll
        for (int k = 0; k < NACC; ++k) acc[k] += (double)p[i * NACC + k];
    }
#pragma unroll
    for (int k = 0; k < NACC; ++k) {
#pragma unroll
        for (int off = 32; off > 0; off >>= 1)
            acc[k] += __shfl_down(acc[k], off);
    }

    if (t != 0) return;

    const double EPS = 1.1920928955078125e-07;  // np.float32 eps
    const double W1 = acc[0];
    const double Sw = acc[1];
    const double inv = 1.0 / (W1 + EPS);
    const double mux[3] = {acc[2] * inv, acc[3] * inv, acc[4] * inv};
    const double muy[3] = {acc[5] * inv, acc[6] * inv, acc[7] * inv};
    const double S0 = Sw * inv;
    const double c2 = 2.0 - S0;

    double S[3][3];
#pragma unroll
    for (int i = 0; i < 3; ++i)
#pragma unroll
        for (int j = 0; j < 3; ++j)
            S[i][j] = acc[8 + i * 3 + j] * inv - muy[i] * mux[j] * c2;

    // A = S^T S (symmetric PSD)
    double A[3][3];
#pragma unroll
    for (int i = 0; i < 3; ++i)
#pragma unroll
        for (int j = 0; j < 3; ++j)
            A[i][j] = S[0][i] * S[0][j] + S[1][i] * S[1][j] + S[2][i] * S[2][j];

    double V[3][3] = {{1, 0, 0}, {0, 1, 0}, {0, 0, 1}};
    for (int sweep = 0; sweep < 30; ++sweep) {
        const double offd = fabs(A[0][1]) + fabs(A[0][2]) + fabs(A[1][2]);
        if (offd == 0.0) break;
        for (int pq = 0; pq < 3; ++pq) {
            const int pi = (pq == 2) ? 1 : 0;
            const int qi = (pq == 0) ? 1 : 2;
            const double apq = A[pi][qi];
            if (fabs(apq) < 1e-300) continue;
            const double theta = (A[qi][qi] - A[pi][pi]) / (2.0 * apq);
            const double tt = copysign(1.0, theta) / (fabs(theta) + sqrt(theta * theta + 1.0));
            const double cc = 1.0 / sqrt(tt * tt + 1.0);
            const double ss = tt * cc;
            const int r = 3 - pi - qi;
            A[pi][pi] -= tt * apq;
            A[qi][qi] += tt * apq;
            A[pi][qi] = A[qi][pi] = 0.0;
            const double arp = A[r][pi], arq = A[r][qi];
            A[r][pi] = A[pi][r] = cc * arp - ss * arq;
            A[r][qi] = A[qi][r] = ss * arp + cc * arq;
#pragma unroll
            for (int k = 0; k < 3; ++k) {
                const double vkp = V[k][pi], vkq = V[k][qi];
                V[k][pi] = cc * vkp - ss * vkq;
                V[k][qi] = ss * vkp + cc * vkq;
            }
        }
    }

    // sort eigenpairs descending
    double lam[3] = {A[0][0], A[1][1], A[2][2]};
    int idx[3] = {0, 1, 2};
    if (lam[idx[0]] < lam[idx[1]]) { int q = idx[0]; idx[0] = idx[1]; idx[1] = q; }
    if (lam[idx[0]] < lam[idx[2]]) { int q = idx[0]; idx[0] = idx[2]; idx[2] = q; }
    if (lam[idx[1]] < lam[idx[2]]) { int q = idx[1]; idx[1] = idx[2]; idx[2] = q; }

    const double v0[3] = {V[0][idx[0]], V[1][idx[0]], V[2][idx[0]]};
    const double v1[3] = {V[0][idx[1]], V[1][idx[1]], V[2][idx[1]]};

    // u0 = normalize(S v0); u1 = orthonormalize(S v1 against u0)
    double u0[3], u1[3];
#pragma unroll
    for (int i = 0; i < 3; ++i) u0[i] = S[i][0] * v0[0] + S[i][1] * v0[1] + S[i][2] * v0[2];
    {
        const double n2 = u0[0] * u0[0] + u0[1] * u0[1] + u0[2] * u0[2];
        const double in0 = 1.0 / sqrt(fmax(n2, 1e-300));
        u0[0] *= in0; u0[1] *= in0; u0[2] *= in0;
    }
#pragma unroll
    for (int i = 0; i < 3; ++i) u1[i] = S[i][0] * v1[0] + S[i][1] * v1[1] + S[i][2] * v1[2];
    {
        const double d01 = u1[0] * u0[0] + u1[1] * u0[1] + u1[2] * u0[2];
        u1[0] -= d01 * u0[0]; u1[1] -= d01 * u0[1]; u1[2] -= d01 * u0[2];
        const double n2 = u1[0] * u1[0] + u1[1] * u1[1] + u1[2] * u1[2];
        const double in1 = 1.0 / sqrt(fmax(n2, 1e-300));
        u1[0] *= in1; u1[1] *= in1; u1[2] *= in1;
    }
    const double u2[3] = {u0[1] * u1[2] - u0[2] * u1[1],
                          u0[2] * u1[0] - u0[0] * u1[2],
                          u0[0] * u1[1] - u0[1] * u1[0]};
    const double v2[3] = {v0[1] * v1[2] - v0[2] * v1[1],
                          v0[2] * v1[0] - v0[0] * v1[2],
                          v0[0] * v1[1] - v0[1] * v1[0]};

    // R = u0 v0^T + u1 v1^T + (u0 x u1)(v0 x v1)^T  == U diag(1,1,d) V^T
    double R[3][3];
#pragma unroll
    for (int i = 0; i < 3; ++i)
#pragma unroll
        for (int j = 0; j < 3; ++j)
            R[i][j] = u0[i] * v0[j] + u1[i] * v1[j] + u2[i] * v2[j];

    double tv[3];
#pragma unroll
    for (int i = 0; i < 3; ++i)
        tv[i] = muy[i] - (R[i][0] * mux[0] + R[i][1] * mux[1] + R[i][2] * mux[2]);

    float* __restrict__ Rout = out + (size_t)b * 9;
#pragma unroll
    for (int i = 0; i < 3; ++i)
#pragma unroll
        for (int j = 0; j < 3; ++j)
            Rout[i * 3 + j] = (float)R[i][j];
    float* __restrict__ tout = out + (size_t)B * 9 + (size_t)b * 3;
#pragma unroll
    for (int i = 0; i < 3; ++i) tout[i] = (float)tv[i];
    out[(size_t)B * 12 + b] = (float)Sw;
}

extern "C" void kernel_launch(void* const* d_in, const int* in_sizes, int n_in,
                              void* d_out, int out_size, void* d_ws, size_t ws_size,
                              hipStream_t stream) {
    const float* xyzs1   = (const float*)d_in[0];
    const float* xyzs2   = (const float*)d_in[1];
    const int*   pairs   = (const int*)d_in[2];
    const float* weights = (const float*)d_in[3];
    float* out = (float*)d_out;

    const int B = out_size / 13;           // 9 + 3 + 1 floats per batch
    const int M = in_sizes[0] / (3 * B);
    const int N = in_sizes[3] / B;

    float* partials = (float*)d_ws;        // B * BPB * NACC floats

    hipLaunchKernelGGL(wp_partials, dim3(B * BPB), dim3(256), 0, stream,
                       xyzs1, xyzs2, pairs, weights, partials, B, M, N);
    hipLaunchKernelGGL(wp_finalize, dim3(B), dim3(64), 0, stream,
                       partials, out, B);
}